// Round 2
// baseline (408.654 us; speedup 1.0000x reference)
//
#include <hip/hip_runtime.h>
#include <hip/hip_fp16.h>
#include <stdint.h>

#define NTOK 16384
#define HID 4096
#define NE 64
#define NQKV 192          // 3*NE
#define TM 64             // tokens per block
#define BK 64             // K-chunk
#define NCHUNK (HID / BK) // 64

typedef _Float16 half8_t __attribute__((ext_vector_type(8)));
typedef _Float16 half4_t __attribute__((ext_vector_type(4)));
typedef float f32x4 __attribute__((ext_vector_type(4)));

#if __has_builtin(__builtin_amdgcn_exp2f)
#define EXP2F(x) __builtin_amdgcn_exp2f(x)
#else
#define EXP2F(x) exp2f(x)
#endif

// ---------------- W fp32 -> fp16 (RTN) ----------------
__global__ void wconvert_kernel(const float* __restrict__ W, _Float16* __restrict__ W16) {
    int i = (blockIdx.x * blockDim.x + threadIdx.x) * 8;
    f32x4 a = *(const f32x4*)(W + i);
    f32x4 b = *(const f32x4*)(W + i + 4);
    half8_t h;
    h[0] = (_Float16)a[0]; h[1] = (_Float16)a[1]; h[2] = (_Float16)a[2]; h[3] = (_Float16)a[3];
    h[4] = (_Float16)b[0]; h[5] = (_Float16)b[1]; h[6] = (_Float16)b[2]; h[7] = (_Float16)b[3];
    *(half8_t*)(W16 + i) = h;
}

// ---------------- fused GEMM + outer-product softmax attention ----------------
// Block: 256 threads (4 waves). Wave w owns token rows [16w,16w+16) x all 192 cols.
// LDS tiles swizzled in 16B chunks: element (row,k) at  row*64 + ((k>>3)^(row&7))*8 + (k&7)
__global__ __launch_bounds__(256, 1) void fused_kernel(const float* __restrict__ X,
                                                       const _Float16* __restrict__ W16,
                                                       float* __restrict__ out) {
    __shared__ __align__(16) _Float16 As[2][TM * BK];    // 2 x 8 KB
    __shared__ __align__(16) _Float16 Bs[2][NQKV * BK];  // 2 x 24 KB
    __shared__ __align__(16) float mixS[TM][NQKV + 4];   // 50 KB

    const int tid  = threadIdx.x;
    const int lane = tid & 63;
    const int wid  = tid >> 6;
    const int tok0 = blockIdx.x * TM;

    // A staging geometry: load inst i covers rows i*16 + (tid>>4), cols (tid&15)*4 (..+3)
    const int arow0 = tid >> 4;               // 0..15
    const int acol  = (tid & 15) * 4;         // 0..60
    const int aphys = ((tid & 15) >> 1) ^ (arow0 & 7);           // 16B chunk after swizzle
    const int adst0 = arow0 * 64 + aphys * 8 + (tid & 1) * 4;    // halves offset
    const float* abase = X + (size_t)(tok0 + arow0) * HID + acol;

    f32x4 acc[12] = {};

    auto stage = [&](int buf, int kc) {
        // ---- A: 64x64 fp32 -> fp16, swizzled reg-stage ----
        const float* ap = abase + kc * BK;
        #pragma unroll
        for (int i = 0; i < 4; ++i) {
            f32x4 f = *(const f32x4*)(ap + (size_t)i * 16 * HID);
            half4_t h;
            h[0] = (_Float16)f[0]; h[1] = (_Float16)f[1];
            h[2] = (_Float16)f[2]; h[3] = (_Float16)f[3];
            *(half4_t*)&As[buf][adst0 + i * 1024] = h;
        }
        // ---- B: 192x64 fp16 via global_load_lds (linear LDS dest, pre-swizzled src) ----
        #pragma unroll
        for (int i = 0; i < 6; ++i) {
            int o  = i * 4096 + wid * 1024 + lane * 16;  // byte offset in 24KB tile
            int r  = o >> 7;                              // row (= qkv col index) 0..191
            int cp = (o >> 4) & 7;                        // physical 16B chunk
            int cl = cp ^ (r & 7);                        // logical chunk to fetch
            const _Float16* src = W16 + (size_t)r * HID + kc * BK + cl * 8;
            char* dst = (char*)(&Bs[buf][0]) + i * 4096 + wid * 1024; // wave-uniform base
            __builtin_amdgcn_global_load_lds(
                (const __attribute__((address_space(1))) uint32_t*)(uintptr_t)(const void*)src,
                (__attribute__((address_space(3))) uint32_t*)(uintptr_t)(void*)dst,
                16, 0, 0);
        }
    };

    auto compute = [&](int buf) {
        const int arow = wid * 16 + (lane & 15);
        #pragma unroll
        for (int kk = 0; kk < 2; ++kk) {
            const int acl = kk * 4 + (lane >> 4);
            half8_t av = *(half8_t*)&As[buf][arow * BK + ((acl ^ (arow & 7)) * 8)];
            #pragma unroll
            for (int j = 0; j < 12; ++j) {
                const int brow = j * 16 + (lane & 15);
                half8_t bv = *(half8_t*)&Bs[buf][brow * BK + ((acl ^ (brow & 7)) * 8)];
                acc[j] = __builtin_amdgcn_mfma_f32_16x16x32_f16(av, bv, acc[j], 0, 0, 0);
            }
        }
    };

    stage(0, 0);
    __syncthreads();
    for (int t = 0; t < NCHUNK; ++t) {
        const int cur = t & 1;
        if (t + 1 < NCHUNK) stage(cur ^ 1, t + 1);
        compute(cur);
        __syncthreads();
    }

    // ---- epilogue: spill acc to LDS (C frag: col=lane&15, row=(lane>>4)*4+reg) ----
    #pragma unroll
    for (int j = 0; j < 12; ++j) {
        #pragma unroll
        for (int rg = 0; rg < 4; ++rg) {
            int row = wid * 16 + (lane >> 4) * 4 + rg;
            int col = j * 16 + (lane & 15);
            mixS[row][col] = acc[j][rg];
        }
    }
    __syncthreads();

    // ---- attention: wave w handles tokens 16w..16w+15, lane = e ----
    const float L2E = 1.44269504088896f;
    for (int tt = 0; tt < 16; ++tt) {
        const int row = wid * 16 + tt;
        float q  = mixS[row][lane];
        float kl = mixS[row][NE + lane];
        float kmax = kl, kmin = kl;
        #pragma unroll
        for (int off = 32; off >= 1; off >>= 1) {
            kmax = fmaxf(kmax, __shfl_xor(kmax, off));
            kmin = fminf(kmin, __shfl_xor(kmin, off));
        }
        float m   = (q >= 0.0f) ? q * kmax : q * kmin;  // exact rowmax (separable)
        float ql  = q * L2E;
        float nml = -m * L2E;
        float sum = 0.0f, av = 0.0f;
        #pragma unroll 4
        for (int f4 = 0; f4 < 16; ++f4) {
            f32x4 kf = *(f32x4*)&mixS[row][NE + f4 * 4];       // uniform -> LDS broadcast
            f32x4 vf = *(f32x4*)&mixS[row][2 * NE + f4 * 4];
            #pragma unroll
            for (int u = 0; u < 4; ++u) {
                float p = EXP2F(fmaf(ql, kf[u], nml));
                sum += p;
                av = fmaf(p, vf[u], av);
            }
        }
        out[(size_t)(tok0 + row) * NE + lane] = av / sum;
    }
}

extern "C" void kernel_launch(void* const* d_in, const int* in_sizes, int n_in,
                              void* d_out, int out_size, void* d_ws, size_t ws_size,
                              hipStream_t stream) {
    const float* X = (const float*)d_in[0];   // [16384, 4096] fp32
    const float* W = (const float*)d_in[1];   // [192, 4096] fp32
    float* out = (float*)d_out;               // [16384, 64] fp32
    _Float16* W16 = (_Float16*)d_ws;          // 1.5 MB scratch

    wconvert_kernel<<<(NQKV * HID) / (256 * 8), 256, 0, stream>>>(W, W16);
    fused_kernel<<<NTOK / TM, 256, 0, stream>>>(X, W16, out);
}

// Round 3
// 399.416 us; speedup vs baseline: 1.0231x; 1.0231x over previous
//
#include <hip/hip_runtime.h>
#include <hip/hip_fp16.h>
#include <stdint.h>

#define NTOK 16384
#define HID 4096
#define NE 64
#define NQKV 192          // 3*NE
#define TM 32             // tokens per block -> 512 blocks = 2 blocks/CU
#define BK 64             // K-chunk
#define NCHUNK (HID / BK) // 64

typedef _Float16 half8_t __attribute__((ext_vector_type(8)));
typedef _Float16 half4_t __attribute__((ext_vector_type(4)));
typedef float f32x4 __attribute__((ext_vector_type(4)));

#if __has_builtin(__builtin_amdgcn_exp2f)
#define EXP2F(x) __builtin_amdgcn_exp2f(x)
#else
#define EXP2F(x) exp2f(x)
#endif

// ---------------- W fp32 -> fp16 (RTN) ----------------
__global__ void wconvert_kernel(const float* __restrict__ W, _Float16* __restrict__ W16) {
    int i = (blockIdx.x * blockDim.x + threadIdx.x) * 8;
    f32x4 a = *(const f32x4*)(W + i);
    f32x4 b = *(const f32x4*)(W + i + 4);
    half8_t h;
    h[0] = (_Float16)a[0]; h[1] = (_Float16)a[1]; h[2] = (_Float16)a[2]; h[3] = (_Float16)a[3];
    h[4] = (_Float16)b[0]; h[5] = (_Float16)b[1]; h[6] = (_Float16)b[2]; h[7] = (_Float16)b[3];
    *(half8_t*)(W16 + i) = h;
}

// ---------------- fused GEMM + outer-product softmax attention ----------------
// 256 threads (4 waves). Wave w: row-group rg=w&1 (16 rows), col-group cg=w>>1 (96 cols).
// LDS tiles swizzled in 16B chunks: element (row,k) at  row*64 + ((k>>3)^(row&7))*8 + (k&7)
// LDS union: As(8K)+Bs(48K) live during K-loop; mixS(24.5K) aliases them after.
__global__ __launch_bounds__(256, 2) void fused_kernel(const float* __restrict__ X,
                                                       const _Float16* __restrict__ W16,
                                                       float* __restrict__ out) {
    __shared__ __align__(16) char smem[57344];
    _Float16* As = (_Float16*)smem;              // [2][TM*BK]   = 2 x 4 KB
    _Float16* Bs = (_Float16*)(smem + 8192);     // [2][NQKV*BK] = 2 x 24 KB
    float* mixS = (float*)smem;                  // [TM][196]    = 24.5 KB (aliases As/Bs)

    const int tid  = threadIdx.x;
    const int lane = tid & 63;
    const int wid  = tid >> 6;
    const int tok0 = blockIdx.x * TM;

    // A staging: load i covers row i*16 + (tid>>4), cols (tid&15)*4 .. +3
    const int arow0 = tid >> 4;               // 0..15
    const int acol  = (tid & 15) * 4;         // 0..60
    const int aphys = ((tid & 15) >> 1) ^ (arow0 & 7);           // 16B chunk after swizzle
    const int adst0 = arow0 * 64 + aphys * 8 + (tid & 1) * 4;
    const float* abase = X + (size_t)(tok0 + arow0) * HID + acol;

    f32x4 acc[6] = {};

    auto stage = [&](int buf, int kc) {
        // ---- A: 32x64 fp32 -> fp16, swizzled reg-stage ----
        const float* ap = abase + kc * BK;
        #pragma unroll
        for (int i = 0; i < 2; ++i) {
            f32x4 f = *(const f32x4*)(ap + (size_t)i * 16 * HID);
            half4_t h;
            h[0] = (_Float16)f[0]; h[1] = (_Float16)f[1];
            h[2] = (_Float16)f[2]; h[3] = (_Float16)f[3];
            *(half4_t*)&As[buf * 2048 + adst0 + i * 1024] = h;
        }
        // ---- B: 192x64 fp16 via global_load_lds (linear LDS dest, pre-swizzled src) ----
        #pragma unroll
        for (int i = 0; i < 6; ++i) {
            int o  = i * 4096 + wid * 1024 + lane * 16;  // byte offset in 24KB tile
            int r  = o >> 7;                              // qkv row 0..191
            int cp = (o >> 4) & 7;                        // physical 16B chunk
            int cl = cp ^ (r & 7);                        // logical chunk to fetch
            const _Float16* src = W16 + (size_t)r * HID + kc * BK + cl * 8;
            char* dst = (char*)Bs + buf * 24576 + i * 4096 + wid * 1024; // wave-uniform base
            __builtin_amdgcn_global_load_lds(
                (const __attribute__((address_space(1))) uint32_t*)(uintptr_t)(const void*)src,
                (__attribute__((address_space(3))) uint32_t*)(uintptr_t)(void*)dst,
                16, 0, 0);
        }
    };

    const int rg = wid & 1;       // row-group (16 rows)
    const int cg = wid >> 1;      // col-group (96 cols)

    auto compute = [&](int buf) {
        const int arow = rg * 16 + (lane & 15);
        #pragma unroll
        for (int kk = 0; kk < 2; ++kk) {
            const int acl = kk * 4 + (lane >> 4);
            half8_t av = *(half8_t*)&As[buf * 2048 + arow * BK + ((acl ^ (arow & 7)) * 8)];
            #pragma unroll
            for (int j = 0; j < 6; ++j) {
                const int brow = cg * 96 + j * 16 + (lane & 15);
                half8_t bv = *(half8_t*)&Bs[buf * 12288 + brow * BK + ((acl ^ (brow & 7)) * 8)];
                acc[j] = __builtin_amdgcn_mfma_f32_16x16x32_f16(av, bv, acc[j], 0, 0, 0);
            }
        }
    };

    stage(0, 0);
    __syncthreads();
    for (int t = 0; t < NCHUNK; ++t) {
        const int cur = t & 1;
        if (t + 1 < NCHUNK) stage(cur ^ 1, t + 1);
        compute(cur);
        __syncthreads();
    }
    // after final barrier: all waves done reading As/Bs -> mixS may alias them

    // ---- epilogue: spill acc to LDS (C frag: col=lane&15, row=(lane>>4)*4+reg) ----
    #pragma unroll
    for (int j = 0; j < 6; ++j) {
        #pragma unroll
        for (int r = 0; r < 4; ++r) {
            int row = rg * 16 + (lane >> 4) * 4 + r;
            int col = cg * 96 + j * 16 + (lane & 15);
            mixS[row * 196 + col] = acc[j][r];
        }
    }
    __syncthreads();

    // ---- attention: wave w handles tokens 8w..8w+7, lane = e ----
    const float L2E = 1.44269504088896f;
    for (int tt = 0; tt < 8; ++tt) {
        const int row = wid * 8 + tt;
        float q  = mixS[row * 196 + lane];
        float kl = mixS[row * 196 + NE + lane];
        float kmax = kl, kmin = kl;
        #pragma unroll
        for (int off = 32; off >= 1; off >>= 1) {
            kmax = fmaxf(kmax, __shfl_xor(kmax, off));
            kmin = fminf(kmin, __shfl_xor(kmin, off));
        }
        float m   = (q >= 0.0f) ? q * kmax : q * kmin;  // exact rowmax (separable)
        float ql  = q * L2E;
        float nml = -m * L2E;
        float sum = 0.0f, av = 0.0f;
        #pragma unroll 4
        for (int f4 = 0; f4 < 16; ++f4) {
            f32x4 kf = *(f32x4*)&mixS[row * 196 + NE + f4 * 4];     // uniform -> broadcast
            f32x4 vf = *(f32x4*)&mixS[row * 196 + 2 * NE + f4 * 4];
            #pragma unroll
            for (int u = 0; u < 4; ++u) {
                float p = EXP2F(fmaf(ql, kf[u], nml));
                sum += p;
                av = fmaf(p, vf[u], av);
            }
        }
        out[(size_t)(tok0 + row) * NE + lane] = av / sum;
    }
}

extern "C" void kernel_launch(void* const* d_in, const int* in_sizes, int n_in,
                              void* d_out, int out_size, void* d_ws, size_t ws_size,
                              hipStream_t stream) {
    const float* X = (const float*)d_in[0];   // [16384, 4096] fp32
    const float* W = (const float*)d_in[1];   // [192, 4096] fp32
    float* out = (float*)d_out;               // [16384, 64] fp32
    _Float16* W16 = (_Float16*)d_ws;          // 1.5 MB scratch

    wconvert_kernel<<<(NQKV * HID) / (256 * 8), 256, 0, stream>>>(W, W16);
    fused_kernel<<<NTOK / TM, 256, 0, stream>>>(X, W16, out);
}